// Round 8
// baseline (2167.928 us; speedup 1.0000x reference)
//
#include <hip/hip_runtime.h>
#include <stdint.h>
#include <stddef.h>

typedef _Float16 f16;
typedef _Float16 f16x8 __attribute__((ext_vector_type(8)));
typedef float    f32x4 __attribute__((ext_vector_type(4)));

#define NB    16384   // batch
#define TT    100     // encoder steps
#define II    6       // input features
#define HH    128     // hidden
#define OLEN  20      // decoder steps
#define OO    2       // output features
#define RR    64      // batch rows per block

// f16-element offsets into workspace (8 recurrent mats are [512][128] = 65536 f16)
#define OFF_WHH0   0
#define OFF_WIH1   65536
#define OFF_WHH1   131072
#define OFF_DWIH0  196608
#define OFF_DWHH0  262144
#define OFF_DWIH1  327680
#define OFF_DWHH1  393216
#define OFF_WIH0P  458752          // [512][8] zero-padded (K=6 -> 8), prescaled
#define OFF_FCW    462848          // [2][128], NOT prescaled
#define OFF_BIAS_B 926208          // byte offset: 4*512 f32 combined prescaled biases
#define WS_BYTES   934400

#define SWZ(r) (((r) & 15) << 3)   // f16-unit XOR swizzle for h tiles

__device__ __forceinline__ float exp2_(float x) {
#if __has_builtin(__builtin_amdgcn_exp2f)
    return __builtin_amdgcn_exp2f(x);
#else
    return exp2f(x);
#endif
}
__device__ __forceinline__ float rcp_(float x) {
#if __has_builtin(__builtin_amdgcn_rcpf)
    return __builtin_amdgcn_rcpf(x);
#else
    return 1.f / x;
#endif
}

// ---------------- weight prep: fp32 -> f16, gate-prescaled; fuse+prescale biases ----
// gate rows (i,f,o) scaled by -log2(e) so sigmoid(z) = rcp(1+exp2(u));
// gate rows (g)     scaled by 2*log2(e) so tanh(z) = 1 - 2*rcp(1+exp2(u)).
__global__ __launch_bounds__(256) void prep_kernel(
    const float* eWih0, const float* eWhh0, const float* eWih1, const float* eWhh1,
    const float* dWih0, const float* dWhh0, const float* dWih1, const float* dWhh1,
    const float* ebi0,  const float* ebh0,  const float* ebi1,  const float* ebh1,
    const float* dbi0,  const float* dbh0,  const float* dbi1,  const float* dbh1,
    const float* fcW,   f16* w16, float* bws)
{
    const float GS0 = -1.4426950408889634f;   // i, f, o
    const float GS2 =  2.8853900817779268f;   // g
    int i0 = blockIdx.x * blockDim.x + threadIdx.x;
    int stride = gridDim.x * blockDim.x;
    const float* srcs[7] = {eWhh0, eWih1, eWhh1, dWih0, dWhh0, dWih1, dWhh1};
    for (int i = i0; i < 7 * 65536; i += stride) {
        int rem = i & 65535;
        float s = ((rem >> 14) == 2) ? GS2 : GS0;
        w16[i] = (f16)(srcs[i >> 16][rem] * s);
    }
    for (int i = i0; i < 512 * 8; i += stride) {
        int n = i >> 3, k = i & 7;
        float s = ((n >> 7) == 2) ? GS2 : GS0;
        w16[OFF_WIH0P + i] = (k < II) ? (f16)(eWih0[n * II + k] * s) : (f16)0.f;
    }
    for (int i = i0; i < OO * HH; i += stride) w16[OFF_FCW + i] = (f16)fcW[i];
    const float* bia[4] = {ebi0, ebi1, dbi0, dbi1};
    const float* bib[4] = {ebh0, ebh1, dbh0, dbh1};
    for (int i = i0; i < 4 * 512; i += stride) {
        int j = i & 511;
        float s = ((j >> 7) == 2) ? GS2 : GS0;
        bws[i] = (bia[i >> 9][j] + bib[i >> 9][j]) * s;
    }
}

// ---------------- main persistent LSTM kernel: 1 block = 64 batch rows ----------------
// R16 baseline 1606us; R23 half-bank pipelining + fc-fold: 1548us (WIN).
// R17-R22: occupancy pinned at 2 waves/SIMD; resident weight banks spill
// (allocator holds ~128 arch / 128 acc split). Remaining lever: scheduling.
// R24: DUAL ACCUMULATOR SETS. In R23 the encoder region chain was
//   GEMM-A -> actA(~1.3Kcy trans) -> GEMM-B(state) -> GEMM-B(input) -> actB
// actA blocked B's MFMAs ONLY because both phases share acc[4][4] (zacc(1)
// WAR on actA's reads). Second accumulator accB[4][4] lands on the ACC side
// of the unified file where 64 regs are free (native MFMA C/D allocation --
// no cross-class copies, unlike R22's failed "+a" data pin): 128 arch +
// 128 acc = 256 = exactly the 2-waves/SIMD budget. B's GEMMs now issue
// right after A's; actA slides into the WIH1 fence region where the
// scheduler interleaves its trans ops with kRL_B(h0)'s MFMAs (separate
// pipes). Encoder chain: 6 half-GEMMs -> actB, actA hidden. Decoder phases
// are barrier-separated (no overlap possible): structure unchanged, phases
// just use the A / B sets respectively.
__global__ __launch_bounds__(512, 2) void lstm_kernel(
    const float* __restrict__ xg, const f16* __restrict__ wsf,
    const float* __restrict__ bws, const float* __restrict__ fcb,
    float* __restrict__ out)
{
    __shared__ __align__(16) f16 h0s[2][RR][HH];     // 32KB, XOR-swizzled
    __shared__ __align__(16) f16 h1s[2][RR][HH];     // 32KB
    __shared__ __align__(16) f16 xs[2][RR][8];       // 2KB
    __shared__ __align__(16) f16 fcws[OO * HH];      // .5KB
    __shared__ float bias_s[4 * 512];                // 8KB
    __shared__ f32x4 c0s[4][512];                    // 32KB cell-0 state (per-thread slots)
    __shared__ f32x4 c1s[4][512];                    // 32KB cell-1 state -> 138.5KB

    const int tid = threadIdx.x;
    const int w   = tid >> 6;      // wave 0..7 -> hidden cols 16w..16w+15
    const int ln  = tid & 63;
    const int l15 = ln & 15;
    const int lg  = ln >> 4;       // lane k-group
    const int r0  = blockIdx.x * RR;

    // ---- init LDS (note: BOTH h1 buffers zeroed -- region 1 reads h1s[1] as h1(-1))
    for (int i = tid; i < OO * HH; i += 512) fcws[i] = wsf[OFF_FCW + i];
    for (int i = tid; i < 4 * 512; i += 512) bias_s[i] = bws[i];
    for (int i = tid; i < RR * HH; i += 512) {
        h0s[0][0][i] = (f16)0.f;
        h1s[0][0][i] = (f16)0.f;
        h1s[1][0][i] = (f16)0.f;
    }
    {
        const f32x4 z4 = {0.f, 0.f, 0.f, 0.f};
        for (int i = tid; i < 4 * 512; i += 512) {
            (&c0s[0][0])[i] = z4;
            (&c1s[0][0])[i] = z4;
        }
    }
    {   // stage x[t=0]
        int r = tid >> 3, k = tid & 7;
        float v = (k < II) ? xg[((size_t)(r0 + r) * TT + 0) * II + k] : 0.f;
        xs[0][r][k] = (f16)v;
    }

    f32x4 accA[4][4];   // [gate][m] phase-A accumulators (64 acc-side regs)
    f32x4 accB[4][4];   // [gate][m] phase-B accumulators (64 acc-side regs)
    f16x8 bankL[4][2];  // [gate][kk=0,1] streamed half-bank (32 arch regs)
    f16x8 bankH[4][2];  // [gate][kk=2,3] streamed half-bank (32 arch regs)
    f16x8 bX[4];        // encoder x-weights (16 arch regs; zero in lanes lg>0)

    {
        const f16x8 z = {};
        #pragma unroll
        for (int g = 0; g < 4; ++g) {
            const int nt = (g << 3) + w;
            bX[g] = (lg == 0)
                ? *(const f16x8*)(wsf + OFF_WIH0P + (size_t)((nt << 4) + l15) * 8)
                : z;
        }
    }

    // stream half of one matrix's B-fragments (kk-major). Offset tied through
    // an empty asm so loads re-execute per call (no hoisting into a
    // persistent spill-prone set -- the R5-R11 failure mode).
    auto loadHalfL = [&](unsigned offElems) {
        unsigned off = offElems;
        asm volatile("" : "+v"(off));
        const f16* W = wsf + off;
        #pragma unroll
        for (int kk = 0; kk < 2; ++kk)
            #pragma unroll
            for (int g = 0; g < 4; ++g) {
                const int nt = (g << 3) + w;
                bankL[g][kk] = *(const f16x8*)(W + (size_t)((nt << 4) + l15) * HH + (kk << 5) + (lg << 3));
            }
    };
    auto loadHalfH = [&](unsigned offElems) {
        unsigned off = offElems;
        asm volatile("" : "+v"(off));
        const f16* W = wsf + off;
        #pragma unroll
        for (int kk = 2; kk < 4; ++kk)
            #pragma unroll
            for (int g = 0; g < 4; ++g) {
                const int nt = (g << 3) + w;
                bankH[g][kk - 2] = *(const f16x8*)(W + (size_t)((nt << 4) + l15) * HH + (kk << 5) + (lg << 3));
            }
    };
    // fence + load: sched_barrier stops the new half-burst's loads from
    // hoisting above the previous consumer of that half (liveness doubling).
    #define LBL(off) do { __builtin_amdgcn_sched_barrier(0); loadHalfL(off); } while (0)
    #define LBH(off) do { __builtin_amdgcn_sched_barrier(0); loadHalfH(off); } while (0)

    auto zaccA = [&](int cell) {
        #pragma unroll
        for (int g = 0; g < 4; ++g) {
            float b = bias_s[(cell << 9) | (g << 7) | (w << 4) | l15];
            f32x4 b4 = {b, b, b, b};
            #pragma unroll
            for (int m = 0; m < 4; ++m) accA[g][m] = b4;
        }
    };
    auto zaccB = [&](int cell) {
        #pragma unroll
        for (int g = 0; g < 4; ++g) {
            float b = bias_s[(cell << 9) | (g << 7) | (w << 4) | l15];
            f32x4 b4 = {b, b, b, b};
            #pragma unroll
            for (int m = 0; m < 4; ++m) accB[g][m] = b4;
        }
    };

    // K=64 half-GEMMs over ALL m-tiles with one half-bank (kk-major), per acc set
    auto kRL_A = [&](const f16* hsrc) {
        #pragma unroll
        for (int kk = 0; kk < 2; ++kk)
            #pragma unroll
            for (int m = 0; m < 4; ++m) {
                int r = (m << 4) + l15;
                int c = ((kk << 5) | (lg << 3)) ^ SWZ(r);
                f16x8 a = *(const f16x8*)(hsrc + (size_t)r * HH + c);
                #pragma unroll
                for (int g = 0; g < 4; ++g)
                    accA[g][m] = __builtin_amdgcn_mfma_f32_16x16x32_f16(a, bankL[g][kk], accA[g][m], 0, 0, 0);
            }
    };
    auto kRH_A = [&](const f16* hsrc) {
        #pragma unroll
        for (int kk = 2; kk < 4; ++kk)
            #pragma unroll
            for (int m = 0; m < 4; ++m) {
                int r = (m << 4) + l15;
                int c = ((kk << 5) | (lg << 3)) ^ SWZ(r);
                f16x8 a = *(const f16x8*)(hsrc + (size_t)r * HH + c);
                #pragma unroll
                for (int g = 0; g < 4; ++g)
                    accA[g][m] = __builtin_amdgcn_mfma_f32_16x16x32_f16(a, bankH[g][kk - 2], accA[g][m], 0, 0, 0);
            }
    };
    auto kRL_B = [&](const f16* hsrc) {
        #pragma unroll
        for (int kk = 0; kk < 2; ++kk)
            #pragma unroll
            for (int m = 0; m < 4; ++m) {
                int r = (m << 4) + l15;
                int c = ((kk << 5) | (lg << 3)) ^ SWZ(r);
                f16x8 a = *(const f16x8*)(hsrc + (size_t)r * HH + c);
                #pragma unroll
                for (int g = 0; g < 4; ++g)
                    accB[g][m] = __builtin_amdgcn_mfma_f32_16x16x32_f16(a, bankL[g][kk], accB[g][m], 0, 0, 0);
            }
    };
    auto kRH_B = [&](const f16* hsrc) {
        #pragma unroll
        for (int kk = 2; kk < 4; ++kk)
            #pragma unroll
            for (int m = 0; m < 4; ++m) {
                int r = (m << 4) + l15;
                int c = ((kk << 5) | (lg << 3)) ^ SWZ(r);
                f16x8 a = *(const f16x8*)(hsrc + (size_t)r * HH + c);
                #pragma unroll
                for (int g = 0; g < 4; ++g)
                    accB[g][m] = __builtin_amdgcn_mfma_f32_16x16x32_f16(a, bankH[g][kk - 2], accB[g][m], 0, 0, 0);
            }
    };

    // encoder x-term: zero-padded K=32 MFMA (real K=6 in lanes lg==0); acc-A
    auto mfx = [&](const f16 (*xsrc)[8]) {
        const f16x8 z = {};
        #pragma unroll
        for (int m = 0; m < 4; ++m) {
            int r = (m << 4) + l15;
            f16x8 a = lg ? z : *(const f16x8*)(&xsrc[r][0]);
            #pragma unroll
            for (int g = 0; g < 4; ++g)
                accA[g][m] = __builtin_amdgcn_mfma_f32_16x16x32_f16(a, bX[g], accA[g][m], 0, 0, 0);
        }
    };

    // gate nonlinearities; c in per-thread LDS slots; h -> hdst (parity-[p^1]
    // buffer, never read in the same region -> race-free). One per acc set.
    auto actA = [&](f32x4 (*cs)[512], f16* hdst) {
        const int col = (w << 4) + l15;
        #pragma unroll
        for (int m = 0; m < 4; ++m) {
            f32x4 cold = cs[m][tid];
            f32x4 cnew;
            #pragma unroll
            for (int q = 0; q < 4; ++q) {
                float si = rcp_(1.f + exp2_(accA[0][m][q]));
                float sf = rcp_(1.f + exp2_(accA[1][m][q]));
                float tg = 1.f - 2.f * rcp_(1.f + exp2_(accA[2][m][q]));
                float so = rcp_(1.f + exp2_(accA[3][m][q]));
                float cn = sf * cold[q] + si * tg;
                cnew[q] = cn;
                float hn = so * (1.f - 2.f * rcp_(1.f + exp2_(2.8853900817779268f * cn)));
                int r = (m << 4) + (lg << 2) + q;
                hdst[(size_t)r * HH + (col ^ SWZ(r))] = (f16)hn;
            }
            cs[m][tid] = cnew;
        }
    };
    auto actB = [&](f32x4 (*cs)[512], f16* hdst) {
        const int col = (w << 4) + l15;
        #pragma unroll
        for (int m = 0; m < 4; ++m) {
            f32x4 cold = cs[m][tid];
            f32x4 cnew;
            #pragma unroll
            for (int q = 0; q < 4; ++q) {
                float si = rcp_(1.f + exp2_(accB[0][m][q]));
                float sf = rcp_(1.f + exp2_(accB[1][m][q]));
                float tg = 1.f - 2.f * rcp_(1.f + exp2_(accB[2][m][q]));
                float so = rcp_(1.f + exp2_(accB[3][m][q]));
                float cn = sf * cold[q] + si * tg;
                cnew[q] = cn;
                float hn = so * (1.f - 2.f * rcp_(1.f + exp2_(2.8853900817779268f * cn)));
                int r = (m << 4) + (lg << 2) + q;
                hdst[(size_t)r * HH + (col ^ SWZ(r))] = (f16)hn;
            }
            cs[m][tid] = cnew;
        }
    };

    LBL(OFF_WHH0);       // prologue: region 0's phase-A L-half
    __syncthreads();     // init visible

    // ============ encoder: 100 pipelined regions + tail, 1 barrier each ============
    // region t: phaseA(t):  accA = b0 + x(t)*Wih0 + h0s[p]*Whh0 -> h0s[p^1], c0
    //           phaseB(t-1):accB = b1 + h1s[p]*Whh1 + h0s[p]*Wih1 -> h1s[p^1], c1
    // (h0(t-1) lives in h0s[p]; h1(t-2) in h1s[p] -- all reads pre-region.)
    // Dual acc: B's GEMMs chain directly after A's; actA overlaps WIH1 bursts
    // and kRL_B(h0)'s MFMAs (same fence region, separate HW pipes).
    for (int t = 0; t < TT; ++t) {
        const int p = t & 1;
        float xv = 0.f;
        if (t + 1 < TT && (tid & 7) < II)
            xv = xg[((size_t)(r0 + (tid >> 3)) * TT + (t + 1)) * II + (tid & 7)];
        LBH(OFF_WHH0);                   // H-burst streams under zaccA+mfx+kRL_A
        zaccA(0);
        mfx(xs[p]);
        kRL_A(&h0s[p][0][0]);            // WHH0-L
        if (t > 0) {
            LBL(OFF_WHH1);               // covered by kRH_A
            kRH_A(&h0s[p][0][0]);        // WHH0-H
            LBH(OFF_WHH1);               // covered by zaccB+kRL_B
            zaccB(1);
            kRL_B(&h1s[p][0][0]);        // WHH1-L (state term h1(t-2))
            LBL(OFF_WIH1);               // covered by kRH_B
            kRH_B(&h1s[p][0][0]);        // WHH1-H
            LBH(OFF_WIH1);               // covered by actA + kRL_B(h0)
            actA(c0s, &h0s[p ^ 1][0][0]);   // off critical path: interleaves w/ kRL_B
            kRL_B(&h0s[p][0][0]);        // WIH1-L (input term h0(t-1), OLD buffer)
            LBL(OFF_WHH0);               // next region's A preload, under kRH_B+actB
            kRH_B(&h0s[p][0][0]);        // WIH1-H
            actB(c1s, &h1s[p ^ 1][0][0]);   // h1(t-1)
        } else {
            kRH_A(&h0s[p][0][0]);        // WHH0-H
            LBL(OFF_WHH0);               // region 1's A preload
            actA(c0s, &h0s[p ^ 1][0][0]);
        }
        if (t + 1 < TT) xs[p ^ 1][tid >> 3][tid & 7] = (f16)xv;
        __builtin_amdgcn_sched_barrier(0);
        __syncthreads();                 // ONE barrier per region
    }
    // tail region: phaseB(99). After loop: h0(99)=h0s[0], h1(98)=h1s[0].
    {
        LBL(OFF_WHH1);
        LBH(OFF_WHH1);
        zaccB(1);
        kRL_B(&h1s[0][0][0]);            // h1(98)
        LBL(OFF_WIH1);
        kRH_B(&h1s[0][0][0]);
        LBH(OFF_WIH1);
        kRL_B(&h0s[0][0][0]);            // h0(99)
        LBL(OFF_DWHH0);                  // decoder phase-A preload, under kRH_B+actB
        kRH_B(&h0s[0][0][0]);
        actB(c1s, &h1s[1][0][0]);        // h1(99) -> h1s[1]
        __builtin_amdgcn_sched_barrier(0);
        __syncthreads();
    }
    // decoder entry: h0 cur = h0s[0], h1 cur = h1s[1]

    float fb = (tid < RR * OO) ? fcb[tid & 1] : 0.f;

    // fc: pred[r][o] = h1d(s) . fc_W[o] + fc_b[o]  (threads 0..127 only)
    auto fcOut = [&](int s, int qq) {
        if (tid < RR * OO) {
            int r = tid >> 1, o = tid & 1;
            float a = fb;
            const f16* hrow = &h1s[qq][r][0];
            #pragma unroll
            for (int ccol = 0; ccol < HH; ccol += 8) {
                int csw = ccol ^ SWZ(r);
                f16x8 hv = *(const f16x8*)(hrow + csw);
                f16x8 wv = *(const f16x8*)(&fcws[o * HH + ccol]);
                #pragma unroll
                for (int j = 0; j < 8; ++j) a += (float)hv[j] * (float)wv[j];
            }
            out[((size_t)(r0 + r) * OLEN + s) * OO + o] = a;
        }
    };

    // ============ decoder: 20 steps, 2 barriers/step ============
    // step s (q=s&1): reads h0s[q], h1s[q^1]; writes h0s[q^1] (A), h1s[q] (B).
    // Strictly serial (B(s) needs A(s)'s h0 through the barrier). fc(s-1) is
    // folded into A(s): reads h1s[q^1] (A-read-only; next written B(s+1)).
    for (int s = 0; s < OLEN; ++s) {
        const int q = s & 1;
        // Phase A: gates2 = b2 + h0d(s-1)*DWhh0 + h1d(s-1)*DWih0 -> h0d(s)
        LBH(OFF_DWHH0);                  // streams under zaccA+fc+kRL_A
        zaccA(2);
        if (s > 0) fcOut(s - 1, q ^ 1);  // waves 0-1 do fc; waves 2-7 proceed
        kRL_A(&h0s[q][0][0]);            // DWHH0-L (preloaded)
        LBL(OFF_DWIH0);
        kRH_A(&h0s[q][0][0]);            // DWHH0-H
        LBH(OFF_DWIH0);
        kRL_A(&h1s[q ^ 1][0][0]);        // DWIH0-L
        kRH_A(&h1s[q ^ 1][0][0]);        // DWIH0-H
        LBL(OFF_DWHH1);                  // phase-B preload, under actA
        actA(c0s, &h0s[q ^ 1][0][0]);
        __builtin_amdgcn_sched_barrier(0);
        __syncthreads();                 // BAR1: h0d(s) published
        // Phase B: gates3 = b3 + h1d(s-1)*DWhh1 + h0d(s)*DWih1 -> h1d(s)
        LBH(OFF_DWHH1);
        zaccB(3);
        kRL_B(&h1s[q ^ 1][0][0]);        // DWHH1-L (preloaded)
        LBL(OFF_DWIH1);
        kRH_B(&h1s[q ^ 1][0][0]);        // DWHH1-H
        LBH(OFF_DWIH1);
        kRL_B(&h0s[q ^ 1][0][0]);        // DWIH1-L
        LBL(OFF_DWHH0);                  // next step's A preload (dead at s=19, harmless)
        kRH_B(&h0s[q ^ 1][0][0]);        // DWIH1-H
        actB(c1s, &h1s[q][0][0]);
        __builtin_amdgcn_sched_barrier(0);
        __syncthreads();                 // BAR2: h1d(s) published
    }
    fcOut(OLEN - 1, (OLEN - 1) & 1);     // last step's fc
    #undef LBL
    #undef LBH
}

extern "C" void kernel_launch(void* const* d_in, const int* in_sizes, int n_in,
                              void* d_out, int out_size, void* d_ws, size_t ws_size,
                              hipStream_t stream) {
    const float* x     = (const float*)d_in[0];
    const float* eWih0 = (const float*)d_in[1];
    const float* eWhh0 = (const float*)d_in[2];
    const float* ebi0  = (const float*)d_in[3];
    const float* ebh0  = (const float*)d_in[4];
    const float* eWih1 = (const float*)d_in[5];
    const float* eWhh1 = (const float*)d_in[6];
    const float* ebi1  = (const float*)d_in[7];
    const float* ebh1  = (const float*)d_in[8];
    const float* dWih0 = (const float*)d_in[9];
    const float* dWhh0 = (const float*)d_in[10];
    const float* dbi0  = (const float*)d_in[11];
    const float* dbh0  = (const float*)d_in[12];
    const float* dWih1 = (const float*)d_in[13];
    const float* dWhh1 = (const float*)d_in[14];
    const float* dbi1  = (const float*)d_in[15];
    const float* dbh1  = (const float*)d_in[16];
    const float* fcW   = (const float*)d_in[17];
    const float* fcb   = (const float*)d_in[18];

    f16*   w16 = (f16*)d_ws;
    float* bws = (float*)((char*)d_ws + OFF_BIAS_B);

    prep_kernel<<<256, 256, 0, stream>>>(eWih0, eWhh0, eWih1, eWhh1,
                                         dWih0, dWhh0, dWih1, dWhh1,
                                         ebi0, ebh0, ebi1, ebh1,
                                         dbi0, dbh0, dbi1, dbh1,
                                         fcW, w16, bws);
    lstm_kernel<<<NB / RR, 512, 0, stream>>>(x, w16, bws, fcb, (float*)d_out);
}